// Round 7
// baseline (466.606 us; speedup 1.0000x reference)
//
#include <hip/hip_runtime.h>
#include <hip/hip_bf16.h>
#include <hip/hip_fp16.h>

// MusicGNN — 3-layer GCN encoder + MLP link predictor.
// N=100000, F_IN=128, HID=64, OUT=32, E=3.2M edges, EL=1M label edges.
// Inputs: float32 (x, weights, biases), int32 (edge indices).
// Output float32: [link_pred (1M) | z (100000*32)] concatenated flat.
//
// R18: (a) packed-fp32 math: gemm inner loops rewritten with
// ext_vector_type(2) accumulators (acc += xb*wpair) so hipcc's
// fp-contract emits v_pk_fma_f32 (gfx950 fp32 peak 157 TF REQUIRES
// VOP3P packed; scalar v_fma is ~half rate). agg accumulators likewise
// v2f (v_pk_add_f32). (b) binB stages the bucket's pairs segment in
// 24KB LDS during the hist pass; scatter pass reads LDS instead of
// re-reading 12.8MB global (fallback to global if seg > 6144; segments
// are 4096+-64, 32 sigma margin). R17 lesson: agg gathers are at a
// random-128B-line regime limit (~7.2 TB/s service) — left unchanged
// structurally. Sort pipeline otherwise = R16.

#define BINA_CHUNK 8192

typedef float v2f __attribute__((ext_vector_type(2)));

// ---------------- per-chunk bucket histogram ----------------

__global__ __launch_bounds__(512) void bhist_kernel(const int* __restrict__ colv,
                                                    int* __restrict__ chist,
                                                    int E, int nbuk) {
    __shared__ int hist[800];
    int base = blockIdx.x * BINA_CHUNK;
    int end = min(base + BINA_CHUNK, E);
    for (int i = threadIdx.x; i < nbuk; i += 512) hist[i] = 0;
    __syncthreads();
    int e = base + threadIdx.x * 4;
    for (; e + 4 <= end; e += 2048) {
        int4 c4 = *(const int4*)&colv[e];
        atomicAdd(&hist[c4.x >> 7], 1);
        atomicAdd(&hist[c4.y >> 7], 1);
        atomicAdd(&hist[c4.z >> 7], 1);
        atomicAdd(&hist[c4.w >> 7], 1);
    }
    for (; e < end; ++e) atomicAdd(&hist[colv[e] >> 7], 1);
    __syncthreads();
    for (int b = threadIdx.x; b < nbuk; b += 512)
        chist[(size_t)blockIdx.x * nbuk + b] = hist[b];
}

// ---------------- column scan: chist[c][b] -> exclusive prefix over c ----------------

__global__ __launch_bounds__(256) void colscan_kernel(int* __restrict__ chist,
                                                      int* __restrict__ bcount,
                                                      int nchunk, int nbuk) {
    __shared__ int sh[256];
    const int b = blockIdx.x;
    const int c0 = threadIdx.x * 4;
    int v[4]; int s = 0;
#pragma unroll
    for (int i = 0; i < 4; ++i) {
        int c = c0 + i;
        v[i] = (c < nchunk) ? chist[(size_t)c * nbuk + b] : 0;
        s += v[i];
    }
    sh[threadIdx.x] = s;
    __syncthreads();
#pragma unroll
    for (int off = 1; off < 256; off <<= 1) {
        int y = (threadIdx.x >= (unsigned)off) ? sh[threadIdx.x - off] : 0;
        __syncthreads();
        sh[threadIdx.x] += y;
        __syncthreads();
    }
    int ex = sh[threadIdx.x] - s;
#pragma unroll
    for (int i = 0; i < 4; ++i) {
        int c = c0 + i;
        if (c < nchunk) { chist[(size_t)c * nbuk + b] = ex; ex += v[i]; }
    }
    if (threadIdx.x == 255) bcount[b] = sh[255];
}

// ---------------- bucket scan ----------------

__global__ __launch_bounds__(256) void bscan_kernel(const int* __restrict__ bcount,
                                                    int* __restrict__ bbase,
                                                    int nbuk, int* __restrict__ offsets, int N) {
    __shared__ int sh[256];
    int base = threadIdx.x * 4;
    int v[4]; int tsum = 0;
#pragma unroll
    for (int i = 0; i < 4; ++i) { int idx = base + i; v[i] = (idx < nbuk) ? bcount[idx] : 0; tsum += v[i]; }
    sh[threadIdx.x] = tsum;
    __syncthreads();
#pragma unroll
    for (int off = 1; off < 256; off <<= 1) {
        int y = (threadIdx.x >= (unsigned)off) ? sh[threadIdx.x - off] : 0;
        __syncthreads();
        sh[threadIdx.x] += y;
        __syncthreads();
    }
    int ex = sh[threadIdx.x] - tsum;
#pragma unroll
    for (int i = 0; i < 4; ++i) {
        int idx = base + i;
        if (idx < nbuk) { bbase[idx] = ex; ex += v[i]; }
        else if (idx == nbuk) { bbase[idx] = ex; offsets[N] = ex; }  // = E
    }
}

// ---------------- Phase A: scatter into buckets (deterministic chunk bases) ----------------

__global__ __launch_bounds__(512) void binA_kernel(const int* __restrict__ rowv,
                                                   const int* __restrict__ colv,
                                                   const int* __restrict__ chist,
                                                   const int* __restrict__ bbase,
                                                   int* __restrict__ pairs,
                                                   int E, int nbuk) {
    __shared__ int pos[800];
    int base = blockIdx.x * BINA_CHUNK;
    int end = min(base + BINA_CHUNK, E);
    for (int b = threadIdx.x; b < nbuk; b += 512)
        pos[b] = bbase[b] + chist[(size_t)blockIdx.x * nbuk + b];
    __syncthreads();
    int e = base + threadIdx.x * 4;
    for (; e + 4 <= end; e += 2048) {
        int4 c4 = *(const int4*)&colv[e];
        int4 r4 = *(const int4*)&rowv[e];
        int g0 = atomicAdd(&pos[c4.x >> 7], 1); pairs[g0] = (r4.x << 7) | (c4.x & 127);
        int g1 = atomicAdd(&pos[c4.y >> 7], 1); pairs[g1] = (r4.y << 7) | (c4.y & 127);
        int g2 = atomicAdd(&pos[c4.z >> 7], 1); pairs[g2] = (r4.z << 7) | (c4.z & 127);
        int g3 = atomicAdd(&pos[c4.w >> 7], 1); pairs[g3] = (r4.w << 7) | (c4.w & 127);
    }
    for (; e < end; ++e) {
        int c = colv[e];
        int g = atomicAdd(&pos[c >> 7], 1);
        pairs[g] = (rowv[e] << 7) | (c & 127);
    }
}

// ---------------- Phase B: per bucket — node hist, scan, offsets+dinv, scatter ----------------
// pairs segment staged in LDS (24KB) during hist pass; scatter reads LDS.

__global__ __launch_bounds__(512) void binB_kernel(const int* __restrict__ pairs,
                                                   const int* __restrict__ bbase,
                                                   int* __restrict__ offsets,
                                                   float* __restrict__ dinv,
                                                   int* __restrict__ edge_src, int N) {
    __shared__ int lcnt[128];
    __shared__ int sc[128];
    __shared__ int lcur[128];
    __shared__ int sp[6144];
    int nodeBeg = blockIdx.x << 7;
    int segBeg = bbase[blockIdx.x];
    int segEnd = bbase[blockIdx.x + 1];
    int len = segEnd - segBeg;
    bool fit = (len <= 6144);
    if (threadIdx.x < 128) lcnt[threadIdx.x] = 0;
    __syncthreads();
    for (int i = threadIdx.x; i < len; i += 512) {
        int p = pairs[segBeg + i];
        if (fit) sp[i] = p;
        atomicAdd(&lcnt[p & 127], 1);
    }
    __syncthreads();
    int v = (threadIdx.x < 128) ? lcnt[threadIdx.x] : 0;
    if (threadIdx.x < 128) sc[threadIdx.x] = v;
    __syncthreads();
    for (int off = 1; off < 128; off <<= 1) {
        int y = 0;
        if (threadIdx.x < 128 && threadIdx.x >= (unsigned)off) y = sc[threadIdx.x - off];
        __syncthreads();
        if (threadIdx.x < 128) sc[threadIdx.x] += y;
        __syncthreads();
    }
    if (threadIdx.x < 128) {
        int ex = sc[threadIdx.x] - v;
        lcur[threadIdx.x] = ex;
        int node = nodeBeg + threadIdx.x;
        if (node < N) {
            offsets[node] = segBeg + ex;
            dinv[node] = rsqrtf((float)(v + 1));
        }
    }
    __syncthreads();
    for (int i = threadIdx.x; i < len; i += 512) {
        int p = fit ? sp[i] : pairs[segBeg + i];
        int rel = atomicAdd(&lcur[p & 127], 1);
        edge_src[segBeg + rel] = p >> 7;
    }
}

// ---------------- GEMM + dinv scale, fp16 out ----------------
// 2 nodes x 4 outs per thread; packed-fp32 (v2f) accumulators.

template <int K, int NOUT>
__global__ __launch_bounds__(32 * (NOUT / 4)) void gemm_scale(const float* __restrict__ in_,
                                                              const float* __restrict__ W,
                                                              const float* __restrict__ dinv,
                                                              __half* __restrict__ out, int N) {
    constexpr int TPB = 32 * (NOUT / 4);      // 512 (NOUT=64) / 256 (NOUT=32)
    constexpr int KS = (K > 64) ? 64 : K;     // stage depth
    constexpr int XPITCH = KS + 4;
    __shared__ float xs[64 * XPITCH];
    __shared__ float ws[KS * NOUT];

    const int tid = threadIdx.x;
    const int nodeBase = blockIdx.x * 64;

    const int jg = tid % (NOUT / 4);
    const int ng = tid / (NOUT / 4);          // 0..31, 2 nodes each

    v2f acc[2][2];
#pragma unroll
    for (int i = 0; i < 2; ++i)
#pragma unroll
        for (int j = 0; j < 2; ++j) acc[i][j] = (v2f){0.f, 0.f};

    for (int kh = 0; kh < K / KS; ++kh) {
        if (kh) __syncthreads();   // previous compute done before overwrite
        for (int i = tid; i < KS * NOUT / 4; i += TPB)
            *(float4*)&ws[i * 4] = *(const float4*)&W[(size_t)kh * KS * NOUT + i * 4];
        for (int i = tid; i < 64 * KS / 4; i += TPB) {
            int row = i / (KS / 4), c = i % (KS / 4);
            int src = nodeBase + row; if (src >= N) src = N - 1;
            *(float4*)&xs[row * XPITCH + c * 4] =
                *(const float4*)&in_[(size_t)src * K + kh * KS + c * 4];
        }
        __syncthreads();

#pragma unroll 4
        for (int kc = 0; kc < KS / 4; ++kc) {
            float4 xv[2], wv[4];
#pragma unroll
            for (int ni = 0; ni < 2; ++ni)
                xv[ni] = *(const float4*)&xs[(ng * 2 + ni) * XPITCH + kc * 4];
#pragma unroll
            for (int t = 0; t < 4; ++t)
                wv[t] = *(const float4*)&ws[(kc * 4 + t) * NOUT + jg * 4];
#pragma unroll
            for (int ni = 0; ni < 2; ++ni) {
                float xk[4] = {xv[ni].x, xv[ni].y, xv[ni].z, xv[ni].w};
#pragma unroll
                for (int t = 0; t < 4; ++t) {
                    v2f xb = {xk[t], xk[t]};
                    v2f wlo = {wv[t].x, wv[t].y};
                    v2f whi = {wv[t].z, wv[t].w};
                    acc[ni][0] += xb * wlo;     // v_pk_fma_f32
                    acc[ni][1] += xb * whi;
                }
            }
        }
    }

#pragma unroll
    for (int ni = 0; ni < 2; ++ni) {
        int node = nodeBase + ng * 2 + ni;
        if (node < N) {
            float dn = dinv[node];
            __half2* op = (__half2*)(out + (size_t)node * NOUT + jg * 4);
            op[0] = __floats2half2_rn(acc[ni][0].x * dn, acc[ni][0].y * dn);
            op[1] = __floats2half2_rn(acc[ni][1].x * dn, acc[ni][1].y * dn);
        }
    }
}

// ---------------- Pull aggregation: float4 (16B) gathers, shfl-broadcast indices ----------------
// v2f accumulators (v_pk_add_f32).

template <int F, bool RELU>
__global__ __launch_bounds__(256) void agg_pull(const __half* __restrict__ h,
                                                const float* __restrict__ dinv,
                                                const float* __restrict__ bias,
                                                const int* __restrict__ edge_src,
                                                const int* __restrict__ offsets,
                                                float* __restrict__ out, int N) {
    constexpr int LPN = F / 8;        // lanes per node: F=64 -> 8, F=32 -> 4
    constexpr int GPW = 64 / LPN;     // nodes per wave: 8 / 16
    constexpr int UNR = LPN;          // edges per iteration per node
    int lane = threadIdx.x & 63;
    int wave = (blockIdx.x * 256 + (int)threadIdx.x) >> 6;
    int g = lane / LPN;
    int fl = lane % LPN;              // 16B slice index within row
    int gbase = lane & ~(LPN - 1);    // first lane of my group
    int node = wave * GPW + g;
    if (node >= N) return;
    float dn = dinv[node];
    int beg = offsets[node], end = offsets[node + 1];
    const float4* __restrict__ hp4 = (const float4*)h;   // row stride = LPN float4s

    // self-loop
    float4 sv = hp4[(size_t)node * LPN + fl];
    float2 s0 = __half22float2(*(const __half2*)&sv.x);
    float2 s1 = __half22float2(*(const __half2*)&sv.y);
    float2 s2 = __half22float2(*(const __half2*)&sv.z);
    float2 s3 = __half22float2(*(const __half2*)&sv.w);
    v2f aA[4] = {{s0.x, s0.y}, {s1.x, s1.y}, {s2.x, s2.y}, {s3.x, s3.y}};
    v2f aB[4] = {{0.f, 0.f}, {0.f, 0.f}, {0.f, 0.f}, {0.f, 0.f}};

    int j = beg;
    for (; j + UNR <= end; j += UNR) {
        int smy = edge_src[j + fl];            // one index per lane
        int sk[UNR];
#pragma unroll
        for (int k = 0; k < UNR; ++k)
            sk[k] = __shfl(smy, gbase + k, 64);
        float4 v[UNR];
#pragma unroll
        for (int k = 0; k < UNR; ++k)
            v[k] = hp4[(size_t)sk[k] * LPN + fl];
#pragma unroll
        for (int k = 0; k < UNR; ++k) {
            float2 p0 = __half22float2(*(const __half2*)&v[k].x);
            float2 p1 = __half22float2(*(const __half2*)&v[k].y);
            float2 p2 = __half22float2(*(const __half2*)&v[k].z);
            float2 p3 = __half22float2(*(const __half2*)&v[k].w);
            v2f* a = (k & 1) ? aB : aA;
            a[0] += (v2f){p0.x, p0.y};
            a[1] += (v2f){p1.x, p1.y};
            a[2] += (v2f){p2.x, p2.y};
            a[3] += (v2f){p3.x, p3.y};
        }
    }
    // tail: r = end - j < UNR
    if (j < end) {
        int r = end - j;
        int smy = (fl < r) ? edge_src[j + fl] : 0;
        for (int k = 0; k < r; ++k) {
            int sk = __shfl(smy, gbase + k, 64);
            float4 v = hp4[(size_t)sk * LPN + fl];
            float2 p0 = __half22float2(*(const __half2*)&v.x);
            float2 p1 = __half22float2(*(const __half2*)&v.y);
            float2 p2 = __half22float2(*(const __half2*)&v.z);
            float2 p3 = __half22float2(*(const __half2*)&v.w);
            v2f* a = (k & 1) ? aB : aA;
            a[0] += (v2f){p0.x, p0.y};
            a[1] += (v2f){p1.x, p1.y};
            a[2] += (v2f){p2.x, p2.y};
            a[3] += (v2f){p3.x, p3.y};
        }
    }

    float4 bva = *(const float4*)&bias[fl * 8];
    float4 bvb = *(const float4*)&bias[fl * 8 + 4];
    v2f t0 = aA[0] + aB[0];
    v2f t1 = aA[1] + aB[1];
    v2f t2 = aA[2] + aB[2];
    v2f t3 = aA[3] + aB[3];
    float r0 = t0.x * dn + bva.x;
    float r1 = t0.y * dn + bva.y;
    float r2 = t1.x * dn + bva.z;
    float r3 = t1.y * dn + bva.w;
    float r4 = t2.x * dn + bvb.x;
    float r5 = t2.y * dn + bvb.y;
    float r6 = t3.x * dn + bvb.z;
    float r7 = t3.y * dn + bvb.w;
    if (RELU) {
        r0 = fmaxf(r0, 0.f); r1 = fmaxf(r1, 0.f); r2 = fmaxf(r2, 0.f); r3 = fmaxf(r3, 0.f);
        r4 = fmaxf(r4, 0.f); r5 = fmaxf(r5, 0.f); r6 = fmaxf(r6, 0.f); r7 = fmaxf(r7, 0.f);
    }
    float* op = &out[(size_t)node * F + fl * 8];
    *(float4*)op = make_float4(r0, r1, r2, r3);
    *(float4*)(op + 4) = make_float4(r4, r5, r6, r7);
}

// ---------------- Decode stage 1: uv[n] = [z@W1_top | z@W1_bot] (fp16 out) ----------------
// 2 nodes per thread, 512 threads; packed-fp32 accumulators.

__global__ __launch_bounds__(512) void gemm_uv(const float* __restrict__ z,   // [N,32]
                                               const float* __restrict__ W1,  // [64,64]
                                               __half* __restrict__ uv, int N) {
    constexpr int ZPITCH = 36;
    __shared__ float zs[64 * ZPITCH];
    __shared__ float ws[64 * 64];
    const int tid = threadIdx.x;
    const int nodeBase = blockIdx.x * 64;

    for (int i = tid; i < 64 * 64 / 4; i += 512)
        *(float4*)&ws[i * 4] = *(const float4*)&W1[i * 4];
    for (int i = tid; i < 64 * 8; i += 512) {
        int row = i / 8, c = i % 8;
        int src = nodeBase + row; if (src >= N) src = N - 1;
        *(float4*)&zs[row * ZPITCH + c * 4] = *(const float4*)&z[(size_t)src * 32 + c * 4];
    }
    __syncthreads();

    const int jg = tid % 16;
    const int ng = tid / 16;     // 0..31, 2 nodes each

    v2f au[2][2], av[2][2];
#pragma unroll
    for (int i = 0; i < 2; ++i)
#pragma unroll
        for (int j = 0; j < 2; ++j) { au[i][j] = (v2f){0.f, 0.f}; av[i][j] = (v2f){0.f, 0.f}; }

#pragma unroll 4
    for (int kc = 0; kc < 8; ++kc) {            // K = 32
        float4 xv[2], wu[4], wv2[4];
#pragma unroll
        for (int ni = 0; ni < 2; ++ni)
            xv[ni] = *(const float4*)&zs[(ng * 2 + ni) * ZPITCH + kc * 4];
#pragma unroll
        for (int t = 0; t < 4; ++t) {
            wu[t]  = *(const float4*)&ws[(kc * 4 + t) * 64 + jg * 4];
            wv2[t] = *(const float4*)&ws[(32 + kc * 4 + t) * 64 + jg * 4];
        }
#pragma unroll
        for (int ni = 0; ni < 2; ++ni) {
            float xk[4] = {xv[ni].x, xv[ni].y, xv[ni].z, xv[ni].w};
#pragma unroll
            for (int t = 0; t < 4; ++t) {
                v2f xb = {xk[t], xk[t]};
                au[ni][0] += xb * (v2f){wu[t].x, wu[t].y};
                au[ni][1] += xb * (v2f){wu[t].z, wu[t].w};
                av[ni][0] += xb * (v2f){wv2[t].x, wv2[t].y};
                av[ni][1] += xb * (v2f){wv2[t].z, wv2[t].w};
            }
        }
    }

#pragma unroll
    for (int ni = 0; ni < 2; ++ni) {
        int node = nodeBase + ng * 2 + ni;
        if (node < N) {
            __half2* pu = (__half2*)(uv + (size_t)node * 128 + jg * 4);
            pu[0] = __floats2half2_rn(au[ni][0].x, au[ni][0].y);
            pu[1] = __floats2half2_rn(au[ni][1].x, au[ni][1].y);
            __half2* pv = (__half2*)(uv + (size_t)node * 128 + 64 + jg * 4);
            pv[0] = __floats2half2_rn(av[ni][0].x, av[ni][0].y);
            pv[1] = __floats2half2_rn(av[ni][1].x, av[ni][1].y);
        }
    }
}

// ---------------- Decode stage 2: link_pred[e] = relu(u[a]+v[b]+b1)·w2 + b2 ----------------
// 8 lanes/edge, float4 (16B) uv loads, 3-deep shuffle reduce.

__global__ __launch_bounds__(256) void decode_edge(const __half* __restrict__ uv,
                                                   const int* __restrict__ eli, int EL,
                                                   const float* __restrict__ lpb1,
                                                   const float* __restrict__ lpW2,
                                                   const float* __restrict__ lpb2,
                                                   float* __restrict__ out) {
    const int sub = threadIdx.x & 7;
    float4 b1a = *(const float4*)&lpb1[sub * 8];
    float4 b1b = *(const float4*)&lpb1[sub * 8 + 4];
    float4 w2a = *(const float4*)&lpW2[sub * 8];
    float4 w2b = *(const float4*)&lpW2[sub * 8 + 4];
    const float b2v = lpb2[0];
    int e = blockIdx.x * 32 + (threadIdx.x >> 3);
    if (e >= EL) return;
    int a = eli[e], b = eli[EL + e];
    float4 ra = *(const float4*)(uv + (size_t)a * 128 + sub * 8);        // 16B: 8 halfs of u[a]
    float4 rb = *(const float4*)(uv + (size_t)b * 128 + 64 + sub * 8);   // 16B: 8 halfs of v[b]
    float2 a01 = __half22float2(*(const __half2*)&ra.x);
    float2 a23 = __half22float2(*(const __half2*)&ra.y);
    float2 a45 = __half22float2(*(const __half2*)&ra.z);
    float2 a67 = __half22float2(*(const __half2*)&ra.w);
    float2 b01 = __half22float2(*(const __half2*)&rb.x);
    float2 b23 = __half22float2(*(const __half2*)&rb.y);
    float2 b45 = __half22float2(*(const __half2*)&rb.z);
    float2 b67 = __half22float2(*(const __half2*)&rb.w);
    float p = fmaxf(a01.x + b01.x + b1a.x, 0.f) * w2a.x;
    p = fmaf(fmaxf(a01.y + b01.y + b1a.y, 0.f), w2a.y, p);
    p = fmaf(fmaxf(a23.x + b23.x + b1a.z, 0.f), w2a.z, p);
    p = fmaf(fmaxf(a23.y + b23.y + b1a.w, 0.f), w2a.w, p);
    p = fmaf(fmaxf(a45.x + b45.x + b1b.x, 0.f), w2b.x, p);
    p = fmaf(fmaxf(a45.y + b45.y + b1b.y, 0.f), w2b.y, p);
    p = fmaf(fmaxf(a67.x + b67.x + b1b.z, 0.f), w2b.z, p);
    p = fmaf(fmaxf(a67.y + b67.y + b1b.w, 0.f), w2b.w, p);
    p += __shfl_down(p, 4, 8);
    p += __shfl_down(p, 2, 8);
    p += __shfl_down(p, 1, 8);
    if (sub == 0) out[e] = p + b2v;
}

// ---------------- launch ----------------

extern "C" void kernel_launch(void* const* d_in, const int* in_sizes, int n_in,
                              void* d_out, int out_size, void* d_ws, size_t ws_size,
                              hipStream_t stream) {
    const float* x    = (const float*)d_in[0];
    const int* ei     = (const int*)d_in[1];
    const int* eli    = (const int*)d_in[2];
    const float* W1   = (const float*)d_in[3];
    const float* b1   = (const float*)d_in[4];
    const float* W2   = (const float*)d_in[5];
    const float* b2   = (const float*)d_in[6];
    const float* W3   = (const float*)d_in[7];
    const float* b3   = (const float*)d_in[8];
    const float* lpW1 = (const float*)d_in[9];
    const float* lpb1 = (const float*)d_in[10];
    const float* lpW2 = (const float*)d_in[11];
    const float* lpb2 = (const float*)d_in[12];

    const int N  = in_sizes[0] / 128;   // 100000
    const int E  = in_sizes[1] / 2;     // 3200000
    const int EL = in_sizes[2] / 2;     // 1000000

    char* p = (char*)d_ws;
    auto alloc = [&](size_t bytes) { void* r = (void*)p; p += (bytes + 255) & ~(size_t)255; return r; };
    float* dinv     = (float*)alloc((size_t)N * 4);
    int*   offsets  = (int*)alloc((size_t)(N + 1) * 4);
    int*   bcount   = (int*)alloc(1024 * 4);
    int*   bbase    = (int*)alloc(1024 * 4);
    int*   edge_src = (int*)alloc((size_t)E * 4);
    __half* bufG    = (__half*)alloc((size_t)N * 64 * 2);   // fp16 messages h'
    float* bufZ     = (float*)alloc((size_t)N * 64 * 4);    // fp32 z1/z2
    __half* uvbuf   = (__half*)alloc((size_t)N * 128 * 2);  // fp16 uv
    int*   pairs    = (int*)uvbuf;  // alias: pairs (12.8MB) dead before gemm_uv writes uv
    int*   chist    = (int*)bufZ;   // alias: chist (1.3MB) dead before agg_pull writes bufZ

    const int* rowv = ei;        // edge_index[0] = source
    const int* colv = ei + E;    // edge_index[1] = target

    int nbuk = (N + 127) / 128;                      // 782
    int nchunk = (E + BINA_CHUNK - 1) / BINA_CHUNK;  // 391 (<=1024 required by colscan)

    bhist_kernel<<<nchunk, 512, 0, stream>>>(colv, chist, E, nbuk);
    colscan_kernel<<<nbuk, 256, 0, stream>>>(chist, bcount, nchunk, nbuk);
    bscan_kernel<<<1, 256, 0, stream>>>(bcount, bbase, nbuk, offsets, N);
    binA_kernel<<<nchunk, 512, 0, stream>>>(rowv, colv, chist, bbase, pairs, E, nbuk);
    binB_kernel<<<nbuk, 512, 0, stream>>>(pairs, bbase, offsets, dinv, edge_src, N);

    float* zout = (float*)d_out + EL;   // z lives in the output tail (float32)

    int gblocks = (N + 63) / 64;  // 1563

    // agg_pull: F=64 -> 8 nodes/wave * 4 waves = 32 nodes/block;
    //           F=32 -> 16 nodes/wave * 4 waves = 64 nodes/block.
    int aggblocks64 = (N + 31) / 32;   // 3125
    int aggblocks32 = (N + 63) / 64;   // 1563

    // layer 1: x[N,128] -> bufG h' (fp16) -> bufZ (fp32, relu)
    gemm_scale<128, 64><<<gblocks, 512, 0, stream>>>(x, W1, dinv, bufG, N);
    agg_pull<64, true><<<aggblocks64, 256, 0, stream>>>(bufG, dinv, b1, edge_src, offsets, bufZ, N);
    // layer 2
    gemm_scale<64, 64><<<gblocks, 512, 0, stream>>>(bufZ, W2, dinv, bufG, N);
    agg_pull<64, true><<<aggblocks64, 256, 0, stream>>>(bufG, dinv, b2, edge_src, offsets, bufZ, N);
    // layer 3: 32-wide, write z directly into d_out tail
    gemm_scale<64, 32><<<gblocks, 256, 0, stream>>>(bufZ, W3, dinv, bufG, N);
    agg_pull<32, false><<<aggblocks32, 256, 0, stream>>>(bufG, dinv, b3, edge_src, offsets, zout, N);
    // decode: per-node uv precompute (fp16), then per-edge gather+epilogue
    gemm_uv<<<gblocks, 512, 0, stream>>>(zout, lpW1, uvbuf, N);
    decode_edge<<<(EL + 31) / 32, 256, 0, stream>>>(uvbuf, eli, EL, lpb1, lpW2, lpb2, (float*)d_out);
}

// Round 8
// 458.431 us; speedup vs baseline: 1.0178x; 1.0178x over previous
//
#include <hip/hip_runtime.h>
#include <hip/hip_bf16.h>
#include <hip/hip_fp16.h>

// MusicGNN — 3-layer GCN encoder + MLP link predictor.
// N=100000, F_IN=128, HID=64, OUT=32, E=3.2M edges, EL=1M label edges.
// Inputs: float32 (x, weights, biases), int32 (edge indices).
// Output float32: [link_pred (1M) | z (100000*32)] concatenated flat.
//
// R19: un-bundle R18's two changes. binB LDS staging REVERTED (24.6KB
// LDS at 512 thr capped binB at 2 blocks/CU on a latency-bound kernel;
// the pairs re-read it avoided was L2-resident anyway -> net regression).
// v2f packed-fp32 gemms KEPT for attribution: if total returns to ~458,
// v2f is neutral/positive; if it stays ~466, v2f is the regression.
// agg_pull/decode_edge confirmed at random-128B-gather floor (~7.2 TB/s
// combined L1/L2/HBM service, 58% L2 hit structural: 12.8MB working set
// vs 4MB per-XCD slice, random graph). Sort pipeline = R16 otherwise.

#define BINA_CHUNK 8192

typedef float v2f __attribute__((ext_vector_type(2)));

// ---------------- per-chunk bucket histogram ----------------

__global__ __launch_bounds__(512) void bhist_kernel(const int* __restrict__ colv,
                                                    int* __restrict__ chist,
                                                    int E, int nbuk) {
    __shared__ int hist[800];
    int base = blockIdx.x * BINA_CHUNK;
    int end = min(base + BINA_CHUNK, E);
    for (int i = threadIdx.x; i < nbuk; i += 512) hist[i] = 0;
    __syncthreads();
    int e = base + threadIdx.x * 4;
    for (; e + 4 <= end; e += 2048) {
        int4 c4 = *(const int4*)&colv[e];
        atomicAdd(&hist[c4.x >> 7], 1);
        atomicAdd(&hist[c4.y >> 7], 1);
        atomicAdd(&hist[c4.z >> 7], 1);
        atomicAdd(&hist[c4.w >> 7], 1);
    }
    for (; e < end; ++e) atomicAdd(&hist[colv[e] >> 7], 1);
    __syncthreads();
    for (int b = threadIdx.x; b < nbuk; b += 512)
        chist[(size_t)blockIdx.x * nbuk + b] = hist[b];
}

// ---------------- column scan: chist[c][b] -> exclusive prefix over c ----------------

__global__ __launch_bounds__(256) void colscan_kernel(int* __restrict__ chist,
                                                      int* __restrict__ bcount,
                                                      int nchunk, int nbuk) {
    __shared__ int sh[256];
    const int b = blockIdx.x;
    const int c0 = threadIdx.x * 4;
    int v[4]; int s = 0;
#pragma unroll
    for (int i = 0; i < 4; ++i) {
        int c = c0 + i;
        v[i] = (c < nchunk) ? chist[(size_t)c * nbuk + b] : 0;
        s += v[i];
    }
    sh[threadIdx.x] = s;
    __syncthreads();
#pragma unroll
    for (int off = 1; off < 256; off <<= 1) {
        int y = (threadIdx.x >= (unsigned)off) ? sh[threadIdx.x - off] : 0;
        __syncthreads();
        sh[threadIdx.x] += y;
        __syncthreads();
    }
    int ex = sh[threadIdx.x] - s;
#pragma unroll
    for (int i = 0; i < 4; ++i) {
        int c = c0 + i;
        if (c < nchunk) { chist[(size_t)c * nbuk + b] = ex; ex += v[i]; }
    }
    if (threadIdx.x == 255) bcount[b] = sh[255];
}

// ---------------- bucket scan ----------------

__global__ __launch_bounds__(256) void bscan_kernel(const int* __restrict__ bcount,
                                                    int* __restrict__ bbase,
                                                    int nbuk, int* __restrict__ offsets, int N) {
    __shared__ int sh[256];
    int base = threadIdx.x * 4;
    int v[4]; int tsum = 0;
#pragma unroll
    for (int i = 0; i < 4; ++i) { int idx = base + i; v[i] = (idx < nbuk) ? bcount[idx] : 0; tsum += v[i]; }
    sh[threadIdx.x] = tsum;
    __syncthreads();
#pragma unroll
    for (int off = 1; off < 256; off <<= 1) {
        int y = (threadIdx.x >= (unsigned)off) ? sh[threadIdx.x - off] : 0;
        __syncthreads();
        sh[threadIdx.x] += y;
        __syncthreads();
    }
    int ex = sh[threadIdx.x] - tsum;
#pragma unroll
    for (int i = 0; i < 4; ++i) {
        int idx = base + i;
        if (idx < nbuk) { bbase[idx] = ex; ex += v[i]; }
        else if (idx == nbuk) { bbase[idx] = ex; offsets[N] = ex; }  // = E
    }
}

// ---------------- Phase A: scatter into buckets (deterministic chunk bases) ----------------

__global__ __launch_bounds__(512) void binA_kernel(const int* __restrict__ rowv,
                                                   const int* __restrict__ colv,
                                                   const int* __restrict__ chist,
                                                   const int* __restrict__ bbase,
                                                   int* __restrict__ pairs,
                                                   int E, int nbuk) {
    __shared__ int pos[800];
    int base = blockIdx.x * BINA_CHUNK;
    int end = min(base + BINA_CHUNK, E);
    for (int b = threadIdx.x; b < nbuk; b += 512)
        pos[b] = bbase[b] + chist[(size_t)blockIdx.x * nbuk + b];
    __syncthreads();
    int e = base + threadIdx.x * 4;
    for (; e + 4 <= end; e += 2048) {
        int4 c4 = *(const int4*)&colv[e];
        int4 r4 = *(const int4*)&rowv[e];
        int g0 = atomicAdd(&pos[c4.x >> 7], 1); pairs[g0] = (r4.x << 7) | (c4.x & 127);
        int g1 = atomicAdd(&pos[c4.y >> 7], 1); pairs[g1] = (r4.y << 7) | (c4.y & 127);
        int g2 = atomicAdd(&pos[c4.z >> 7], 1); pairs[g2] = (r4.z << 7) | (c4.z & 127);
        int g3 = atomicAdd(&pos[c4.w >> 7], 1); pairs[g3] = (r4.w << 7) | (c4.w & 127);
    }
    for (; e < end; ++e) {
        int c = colv[e];
        int g = atomicAdd(&pos[c >> 7], 1);
        pairs[g] = (rowv[e] << 7) | (c & 127);
    }
}

// ---------------- Phase B: per bucket — node hist, scan, offsets+dinv, scatter ----------------

__global__ __launch_bounds__(512) void binB_kernel(const int* __restrict__ pairs,
                                                   const int* __restrict__ bbase,
                                                   int* __restrict__ offsets,
                                                   float* __restrict__ dinv,
                                                   int* __restrict__ edge_src, int N) {
    __shared__ int lcnt[128];
    __shared__ int sc[128];
    __shared__ int lcur[128];
    int nodeBeg = blockIdx.x << 7;
    int segBeg = bbase[blockIdx.x];
    int segEnd = bbase[blockIdx.x + 1];
    if (threadIdx.x < 128) lcnt[threadIdx.x] = 0;
    __syncthreads();
    for (int e = segBeg + threadIdx.x; e < segEnd; e += 512)
        atomicAdd(&lcnt[pairs[e] & 127], 1);
    __syncthreads();
    int v = (threadIdx.x < 128) ? lcnt[threadIdx.x] : 0;
    if (threadIdx.x < 128) sc[threadIdx.x] = v;
    __syncthreads();
    for (int off = 1; off < 128; off <<= 1) {
        int y = 0;
        if (threadIdx.x < 128 && threadIdx.x >= (unsigned)off) y = sc[threadIdx.x - off];
        __syncthreads();
        if (threadIdx.x < 128) sc[threadIdx.x] += y;
        __syncthreads();
    }
    if (threadIdx.x < 128) {
        int ex = sc[threadIdx.x] - v;
        lcur[threadIdx.x] = ex;
        int node = nodeBeg + threadIdx.x;
        if (node < N) {
            offsets[node] = segBeg + ex;
            dinv[node] = rsqrtf((float)(v + 1));
        }
    }
    __syncthreads();
    for (int e = segBeg + threadIdx.x; e < segEnd; e += 512) {
        int p = pairs[e];
        int rel = atomicAdd(&lcur[p & 127], 1);
        edge_src[segBeg + rel] = p >> 7;
    }
}

// ---------------- GEMM + dinv scale, fp16 out ----------------
// 2 nodes x 4 outs per thread; packed-fp32 (v2f) accumulators.

template <int K, int NOUT>
__global__ __launch_bounds__(32 * (NOUT / 4)) void gemm_scale(const float* __restrict__ in_,
                                                              const float* __restrict__ W,
                                                              const float* __restrict__ dinv,
                                                              __half* __restrict__ out, int N) {
    constexpr int TPB = 32 * (NOUT / 4);      // 512 (NOUT=64) / 256 (NOUT=32)
    constexpr int KS = (K > 64) ? 64 : K;     // stage depth
    constexpr int XPITCH = KS + 4;
    __shared__ float xs[64 * XPITCH];
    __shared__ float ws[KS * NOUT];

    const int tid = threadIdx.x;
    const int nodeBase = blockIdx.x * 64;

    const int jg = tid % (NOUT / 4);
    const int ng = tid / (NOUT / 4);          // 0..31, 2 nodes each

    v2f acc[2][2];
#pragma unroll
    for (int i = 0; i < 2; ++i)
#pragma unroll
        for (int j = 0; j < 2; ++j) acc[i][j] = (v2f){0.f, 0.f};

    for (int kh = 0; kh < K / KS; ++kh) {
        if (kh) __syncthreads();   // previous compute done before overwrite
        for (int i = tid; i < KS * NOUT / 4; i += TPB)
            *(float4*)&ws[i * 4] = *(const float4*)&W[(size_t)kh * KS * NOUT + i * 4];
        for (int i = tid; i < 64 * KS / 4; i += TPB) {
            int row = i / (KS / 4), c = i % (KS / 4);
            int src = nodeBase + row; if (src >= N) src = N - 1;
            *(float4*)&xs[row * XPITCH + c * 4] =
                *(const float4*)&in_[(size_t)src * K + kh * KS + c * 4];
        }
        __syncthreads();

#pragma unroll 4
        for (int kc = 0; kc < KS / 4; ++kc) {
            float4 xv[2], wv[4];
#pragma unroll
            for (int ni = 0; ni < 2; ++ni)
                xv[ni] = *(const float4*)&xs[(ng * 2 + ni) * XPITCH + kc * 4];
#pragma unroll
            for (int t = 0; t < 4; ++t)
                wv[t] = *(const float4*)&ws[(kc * 4 + t) * NOUT + jg * 4];
#pragma unroll
            for (int ni = 0; ni < 2; ++ni) {
                float xk[4] = {xv[ni].x, xv[ni].y, xv[ni].z, xv[ni].w};
#pragma unroll
                for (int t = 0; t < 4; ++t) {
                    v2f xb = {xk[t], xk[t]};
                    v2f wlo = {wv[t].x, wv[t].y};
                    v2f whi = {wv[t].z, wv[t].w};
                    acc[ni][0] += xb * wlo;     // v_pk_fma_f32
                    acc[ni][1] += xb * whi;
                }
            }
        }
    }

#pragma unroll
    for (int ni = 0; ni < 2; ++ni) {
        int node = nodeBase + ng * 2 + ni;
        if (node < N) {
            float dn = dinv[node];
            __half2* op = (__half2*)(out + (size_t)node * NOUT + jg * 4);
            op[0] = __floats2half2_rn(acc[ni][0].x * dn, acc[ni][0].y * dn);
            op[1] = __floats2half2_rn(acc[ni][1].x * dn, acc[ni][1].y * dn);
        }
    }
}

// ---------------- Pull aggregation: float4 (16B) gathers, shfl-broadcast indices ----------------
// v2f accumulators (v_pk_add_f32).

template <int F, bool RELU>
__global__ __launch_bounds__(256) void agg_pull(const __half* __restrict__ h,
                                                const float* __restrict__ dinv,
                                                const float* __restrict__ bias,
                                                const int* __restrict__ edge_src,
                                                const int* __restrict__ offsets,
                                                float* __restrict__ out, int N) {
    constexpr int LPN = F / 8;        // lanes per node: F=64 -> 8, F=32 -> 4
    constexpr int GPW = 64 / LPN;     // nodes per wave: 8 / 16
    constexpr int UNR = LPN;          // edges per iteration per node
    int lane = threadIdx.x & 63;
    int wave = (blockIdx.x * 256 + (int)threadIdx.x) >> 6;
    int g = lane / LPN;
    int fl = lane % LPN;              // 16B slice index within row
    int gbase = lane & ~(LPN - 1);    // first lane of my group
    int node = wave * GPW + g;
    if (node >= N) return;
    float dn = dinv[node];
    int beg = offsets[node], end = offsets[node + 1];
    const float4* __restrict__ hp4 = (const float4*)h;   // row stride = LPN float4s

    // self-loop
    float4 sv = hp4[(size_t)node * LPN + fl];
    float2 s0 = __half22float2(*(const __half2*)&sv.x);
    float2 s1 = __half22float2(*(const __half2*)&sv.y);
    float2 s2 = __half22float2(*(const __half2*)&sv.z);
    float2 s3 = __half22float2(*(const __half2*)&sv.w);
    v2f aA[4] = {{s0.x, s0.y}, {s1.x, s1.y}, {s2.x, s2.y}, {s3.x, s3.y}};
    v2f aB[4] = {{0.f, 0.f}, {0.f, 0.f}, {0.f, 0.f}, {0.f, 0.f}};

    int j = beg;
    for (; j + UNR <= end; j += UNR) {
        int smy = edge_src[j + fl];            // one index per lane
        int sk[UNR];
#pragma unroll
        for (int k = 0; k < UNR; ++k)
            sk[k] = __shfl(smy, gbase + k, 64);
        float4 v[UNR];
#pragma unroll
        for (int k = 0; k < UNR; ++k)
            v[k] = hp4[(size_t)sk[k] * LPN + fl];
#pragma unroll
        for (int k = 0; k < UNR; ++k) {
            float2 p0 = __half22float2(*(const __half2*)&v[k].x);
            float2 p1 = __half22float2(*(const __half2*)&v[k].y);
            float2 p2 = __half22float2(*(const __half2*)&v[k].z);
            float2 p3 = __half22float2(*(const __half2*)&v[k].w);
            v2f* a = (k & 1) ? aB : aA;
            a[0] += (v2f){p0.x, p0.y};
            a[1] += (v2f){p1.x, p1.y};
            a[2] += (v2f){p2.x, p2.y};
            a[3] += (v2f){p3.x, p3.y};
        }
    }
    // tail: r = end - j < UNR
    if (j < end) {
        int r = end - j;
        int smy = (fl < r) ? edge_src[j + fl] : 0;
        for (int k = 0; k < r; ++k) {
            int sk = __shfl(smy, gbase + k, 64);
            float4 v = hp4[(size_t)sk * LPN + fl];
            float2 p0 = __half22float2(*(const __half2*)&v.x);
            float2 p1 = __half22float2(*(const __half2*)&v.y);
            float2 p2 = __half22float2(*(const __half2*)&v.z);
            float2 p3 = __half22float2(*(const __half2*)&v.w);
            v2f* a = (k & 1) ? aB : aA;
            a[0] += (v2f){p0.x, p0.y};
            a[1] += (v2f){p1.x, p1.y};
            a[2] += (v2f){p2.x, p2.y};
            a[3] += (v2f){p3.x, p3.y};
        }
    }

    float4 bva = *(const float4*)&bias[fl * 8];
    float4 bvb = *(const float4*)&bias[fl * 8 + 4];
    v2f t0 = aA[0] + aB[0];
    v2f t1 = aA[1] + aB[1];
    v2f t2 = aA[2] + aB[2];
    v2f t3 = aA[3] + aB[3];
    float r0 = t0.x * dn + bva.x;
    float r1 = t0.y * dn + bva.y;
    float r2 = t1.x * dn + bva.z;
    float r3 = t1.y * dn + bva.w;
    float r4 = t2.x * dn + bvb.x;
    float r5 = t2.y * dn + bvb.y;
    float r6 = t3.x * dn + bvb.z;
    float r7 = t3.y * dn + bvb.w;
    if (RELU) {
        r0 = fmaxf(r0, 0.f); r1 = fmaxf(r1, 0.f); r2 = fmaxf(r2, 0.f); r3 = fmaxf(r3, 0.f);
        r4 = fmaxf(r4, 0.f); r5 = fmaxf(r5, 0.f); r6 = fmaxf(r6, 0.f); r7 = fmaxf(r7, 0.f);
    }
    float* op = &out[(size_t)node * F + fl * 8];
    *(float4*)op = make_float4(r0, r1, r2, r3);
    *(float4*)(op + 4) = make_float4(r4, r5, r6, r7);
}

// ---------------- Decode stage 1: uv[n] = [z@W1_top | z@W1_bot] (fp16 out) ----------------
// 2 nodes per thread, 512 threads; packed-fp32 accumulators.

__global__ __launch_bounds__(512) void gemm_uv(const float* __restrict__ z,   // [N,32]
                                               const float* __restrict__ W1,  // [64,64]
                                               __half* __restrict__ uv, int N) {
    constexpr int ZPITCH = 36;
    __shared__ float zs[64 * ZPITCH];
    __shared__ float ws[64 * 64];
    const int tid = threadIdx.x;
    const int nodeBase = blockIdx.x * 64;

    for (int i = tid; i < 64 * 64 / 4; i += 512)
        *(float4*)&ws[i * 4] = *(const float4*)&W1[i * 4];
    for (int i = tid; i < 64 * 8; i += 512) {
        int row = i / 8, c = i % 8;
        int src = nodeBase + row; if (src >= N) src = N - 1;
        *(float4*)&zs[row * ZPITCH + c * 4] = *(const float4*)&z[(size_t)src * 32 + c * 4];
    }
    __syncthreads();

    const int jg = tid % 16;
    const int ng = tid / 16;     // 0..31, 2 nodes each

    v2f au[2][2], av[2][2];
#pragma unroll
    for (int i = 0; i < 2; ++i)
#pragma unroll
        for (int j = 0; j < 2; ++j) { au[i][j] = (v2f){0.f, 0.f}; av[i][j] = (v2f){0.f, 0.f}; }

#pragma unroll 4
    for (int kc = 0; kc < 8; ++kc) {            // K = 32
        float4 xv[2], wu[4], wv2[4];
#pragma unroll
        for (int ni = 0; ni < 2; ++ni)
            xv[ni] = *(const float4*)&zs[(ng * 2 + ni) * ZPITCH + kc * 4];
#pragma unroll
        for (int t = 0; t < 4; ++t) {
            wu[t]  = *(const float4*)&ws[(kc * 4 + t) * 64 + jg * 4];
            wv2[t] = *(const float4*)&ws[(32 + kc * 4 + t) * 64 + jg * 4];
        }
#pragma unroll
        for (int ni = 0; ni < 2; ++ni) {
            float xk[4] = {xv[ni].x, xv[ni].y, xv[ni].z, xv[ni].w};
#pragma unroll
            for (int t = 0; t < 4; ++t) {
                v2f xb = {xk[t], xk[t]};
                au[ni][0] += xb * (v2f){wu[t].x, wu[t].y};
                au[ni][1] += xb * (v2f){wu[t].z, wu[t].w};
                av[ni][0] += xb * (v2f){wv2[t].x, wv2[t].y};
                av[ni][1] += xb * (v2f){wv2[t].z, wv2[t].w};
            }
        }
    }

#pragma unroll
    for (int ni = 0; ni < 2; ++ni) {
        int node = nodeBase + ng * 2 + ni;
        if (node < N) {
            __half2* pu = (__half2*)(uv + (size_t)node * 128 + jg * 4);
            pu[0] = __floats2half2_rn(au[ni][0].x, au[ni][0].y);
            pu[1] = __floats2half2_rn(au[ni][1].x, au[ni][1].y);
            __half2* pv = (__half2*)(uv + (size_t)node * 128 + 64 + jg * 4);
            pv[0] = __floats2half2_rn(av[ni][0].x, av[ni][0].y);
            pv[1] = __floats2half2_rn(av[ni][1].x, av[ni][1].y);
        }
    }
}

// ---------------- Decode stage 2: link_pred[e] = relu(u[a]+v[b]+b1)·w2 + b2 ----------------
// 8 lanes/edge, float4 (16B) uv loads, 3-deep shuffle reduce.

__global__ __launch_bounds__(256) void decode_edge(const __half* __restrict__ uv,
                                                   const int* __restrict__ eli, int EL,
                                                   const float* __restrict__ lpb1,
                                                   const float* __restrict__ lpW2,
                                                   const float* __restrict__ lpb2,
                                                   float* __restrict__ out) {
    const int sub = threadIdx.x & 7;
    float4 b1a = *(const float4*)&lpb1[sub * 8];
    float4 b1b = *(const float4*)&lpb1[sub * 8 + 4];
    float4 w2a = *(const float4*)&lpW2[sub * 8];
    float4 w2b = *(const float4*)&lpW2[sub * 8 + 4];
    const float b2v = lpb2[0];
    int e = blockIdx.x * 32 + (threadIdx.x >> 3);
    if (e >= EL) return;
    int a = eli[e], b = eli[EL + e];
    float4 ra = *(const float4*)(uv + (size_t)a * 128 + sub * 8);        // 16B: 8 halfs of u[a]
    float4 rb = *(const float4*)(uv + (size_t)b * 128 + 64 + sub * 8);   // 16B: 8 halfs of v[b]
    float2 a01 = __half22float2(*(const __half2*)&ra.x);
    float2 a23 = __half22float2(*(const __half2*)&ra.y);
    float2 a45 = __half22float2(*(const __half2*)&ra.z);
    float2 a67 = __half22float2(*(const __half2*)&ra.w);
    float2 b01 = __half22float2(*(const __half2*)&rb.x);
    float2 b23 = __half22float2(*(const __half2*)&rb.y);
    float2 b45 = __half22float2(*(const __half2*)&rb.z);
    float2 b67 = __half22float2(*(const __half2*)&rb.w);
    float p = fmaxf(a01.x + b01.x + b1a.x, 0.f) * w2a.x;
    p = fmaf(fmaxf(a01.y + b01.y + b1a.y, 0.f), w2a.y, p);
    p = fmaf(fmaxf(a23.x + b23.x + b1a.z, 0.f), w2a.z, p);
    p = fmaf(fmaxf(a23.y + b23.y + b1a.w, 0.f), w2a.w, p);
    p = fmaf(fmaxf(a45.x + b45.x + b1b.x, 0.f), w2b.x, p);
    p = fmaf(fmaxf(a45.y + b45.y + b1b.y, 0.f), w2b.y, p);
    p = fmaf(fmaxf(a67.x + b67.x + b1b.z, 0.f), w2b.z, p);
    p = fmaf(fmaxf(a67.y + b67.y + b1b.w, 0.f), w2b.w, p);
    p += __shfl_down(p, 4, 8);
    p += __shfl_down(p, 2, 8);
    p += __shfl_down(p, 1, 8);
    if (sub == 0) out[e] = p + b2v;
}

// ---------------- launch ----------------

extern "C" void kernel_launch(void* const* d_in, const int* in_sizes, int n_in,
                              void* d_out, int out_size, void* d_ws, size_t ws_size,
                              hipStream_t stream) {
    const float* x    = (const float*)d_in[0];
    const int* ei     = (const int*)d_in[1];
    const int* eli    = (const int*)d_in[2];
    const float* W1   = (const float*)d_in[3];
    const float* b1   = (const float*)d_in[4];
    const float* W2   = (const float*)d_in[5];
    const float* b2   = (const float*)d_in[6];
    const float* W3   = (const float*)d_in[7];
    const float* b3   = (const float*)d_in[8];
    const float* lpW1 = (const float*)d_in[9];
    const float* lpb1 = (const float*)d_in[10];
    const float* lpW2 = (const float*)d_in[11];
    const float* lpb2 = (const float*)d_in[12];

    const int N  = in_sizes[0] / 128;   // 100000
    const int E  = in_sizes[1] / 2;     // 3200000
    const int EL = in_sizes[2] / 2;     // 1000000

    char* p = (char*)d_ws;
    auto alloc = [&](size_t bytes) { void* r = (void*)p; p += (bytes + 255) & ~(size_t)255; return r; };
    float* dinv     = (float*)alloc((size_t)N * 4);
    int*   offsets  = (int*)alloc((size_t)(N + 1) * 4);
    int*   bcount   = (int*)alloc(1024 * 4);
    int*   bbase    = (int*)alloc(1024 * 4);
    int*   edge_src = (int*)alloc((size_t)E * 4);
    __half* bufG    = (__half*)alloc((size_t)N * 64 * 2);   // fp16 messages h'
    float* bufZ     = (float*)alloc((size_t)N * 64 * 4);    // fp32 z1/z2
    __half* uvbuf   = (__half*)alloc((size_t)N * 128 * 2);  // fp16 uv
    int*   pairs    = (int*)uvbuf;  // alias: pairs (12.8MB) dead before gemm_uv writes uv
    int*   chist    = (int*)bufZ;   // alias: chist (1.3MB) dead before agg_pull writes bufZ

    const int* rowv = ei;        // edge_index[0] = source
    const int* colv = ei + E;    // edge_index[1] = target

    int nbuk = (N + 127) / 128;                      // 782
    int nchunk = (E + BINA_CHUNK - 1) / BINA_CHUNK;  // 391 (<=1024 required by colscan)

    bhist_kernel<<<nchunk, 512, 0, stream>>>(colv, chist, E, nbuk);
    colscan_kernel<<<nbuk, 256, 0, stream>>>(chist, bcount, nchunk, nbuk);
    bscan_kernel<<<1, 256, 0, stream>>>(bcount, bbase, nbuk, offsets, N);
    binA_kernel<<<nchunk, 512, 0, stream>>>(rowv, colv, chist, bbase, pairs, E, nbuk);
    binB_kernel<<<nbuk, 512, 0, stream>>>(pairs, bbase, offsets, dinv, edge_src, N);

    float* zout = (float*)d_out + EL;   // z lives in the output tail (float32)

    int gblocks = (N + 63) / 64;  // 1563

    // agg_pull: F=64 -> 8 nodes/wave * 4 waves = 32 nodes/block;
    //           F=32 -> 16 nodes/wave * 4 waves = 64 nodes/block.
    int aggblocks64 = (N + 31) / 32;   // 3125
    int aggblocks32 = (N + 63) / 64;   // 1563

    // layer 1: x[N,128] -> bufG h' (fp16) -> bufZ (fp32, relu)
    gemm_scale<128, 64><<<gblocks, 512, 0, stream>>>(x, W1, dinv, bufG, N);
    agg_pull<64, true><<<aggblocks64, 256, 0, stream>>>(bufG, dinv, b1, edge_src, offsets, bufZ, N);
    // layer 2
    gemm_scale<64, 64><<<gblocks, 512, 0, stream>>>(bufZ, W2, dinv, bufG, N);
    agg_pull<64, true><<<aggblocks64, 256, 0, stream>>>(bufG, dinv, b2, edge_src, offsets, bufZ, N);
    // layer 3: 32-wide, write z directly into d_out tail
    gemm_scale<64, 32><<<gblocks, 256, 0, stream>>>(bufZ, W3, dinv, bufG, N);
    agg_pull<32, false><<<aggblocks32, 256, 0, stream>>>(bufG, dinv, b3, edge_src, offsets, zout, N);
    // decode: per-node uv precompute (fp16), then per-edge gather+epilogue
    gemm_uv<<<gblocks, 512, 0, stream>>>(zout, lpW1, uvbuf, N);
    decode_edge<<<(EL + 31) / 32, 256, 0, stream>>>(uvbuf, eli, EL, lpb1, lpW2, lpb2, (float*)d_out);
}

// Round 9
// 445.866 us; speedup vs baseline: 1.0465x; 1.0282x over previous
//
#include <hip/hip_runtime.h>
#include <hip/hip_bf16.h>
#include <hip/hip_fp16.h>

// MusicGNN — 3-layer GCN encoder + MLP link predictor.
// N=100000, F_IN=128, HID=64, OUT=32, E=3.2M edges, EL=1M label edges.
// Inputs: float32 (x, weights, biases), int32 (edge indices).
// Output float32: [link_pred (1M) | z (100000*32)] concatenated flat.
//
// R20: bucket widened 128->256 nodes (nbuk=391). binA's (chunk,bucket)
// write slices double to ~84B, further cutting dirty-line amplification
// (R0: 21B slices = 5x WRITE amp; R16: 42B paid ~10us). chist halves to
// 612KB; bhist/binA LDS arrays halve; binB now 391 blocks x ~8192-edge
// segments with 256-entry node-local arrays. pairs = (row<<8)|(col&255).
// v2f packed-fp32 gemms kept (R19: neutral). agg/decode at gather floor
// (R17/R19). Everything outside the sort byte-identical to R19.

#define BINA_CHUNK 8192
#define BSHIFT 8            // bucket = 256 nodes
#define BMASK 255

typedef float v2f __attribute__((ext_vector_type(2)));

// ---------------- per-chunk bucket histogram ----------------

__global__ __launch_bounds__(512) void bhist_kernel(const int* __restrict__ colv,
                                                    int* __restrict__ chist,
                                                    int E, int nbuk) {
    __shared__ int hist[400];
    int base = blockIdx.x * BINA_CHUNK;
    int end = min(base + BINA_CHUNK, E);
    for (int i = threadIdx.x; i < nbuk; i += 512) hist[i] = 0;
    __syncthreads();
    int e = base + threadIdx.x * 4;
    for (; e + 4 <= end; e += 2048) {
        int4 c4 = *(const int4*)&colv[e];
        atomicAdd(&hist[c4.x >> BSHIFT], 1);
        atomicAdd(&hist[c4.y >> BSHIFT], 1);
        atomicAdd(&hist[c4.z >> BSHIFT], 1);
        atomicAdd(&hist[c4.w >> BSHIFT], 1);
    }
    for (; e < end; ++e) atomicAdd(&hist[colv[e] >> BSHIFT], 1);
    __syncthreads();
    for (int b = threadIdx.x; b < nbuk; b += 512)
        chist[(size_t)blockIdx.x * nbuk + b] = hist[b];
}

// ---------------- column scan: chist[c][b] -> exclusive prefix over c ----------------

__global__ __launch_bounds__(256) void colscan_kernel(int* __restrict__ chist,
                                                      int* __restrict__ bcount,
                                                      int nchunk, int nbuk) {
    __shared__ int sh[256];
    const int b = blockIdx.x;
    const int c0 = threadIdx.x * 4;
    int v[4]; int s = 0;
#pragma unroll
    for (int i = 0; i < 4; ++i) {
        int c = c0 + i;
        v[i] = (c < nchunk) ? chist[(size_t)c * nbuk + b] : 0;
        s += v[i];
    }
    sh[threadIdx.x] = s;
    __syncthreads();
#pragma unroll
    for (int off = 1; off < 256; off <<= 1) {
        int y = (threadIdx.x >= (unsigned)off) ? sh[threadIdx.x - off] : 0;
        __syncthreads();
        sh[threadIdx.x] += y;
        __syncthreads();
    }
    int ex = sh[threadIdx.x] - s;
#pragma unroll
    for (int i = 0; i < 4; ++i) {
        int c = c0 + i;
        if (c < nchunk) { chist[(size_t)c * nbuk + b] = ex; ex += v[i]; }
    }
    if (threadIdx.x == 255) bcount[b] = sh[255];
}

// ---------------- bucket scan ----------------

__global__ __launch_bounds__(256) void bscan_kernel(const int* __restrict__ bcount,
                                                    int* __restrict__ bbase,
                                                    int nbuk, int* __restrict__ offsets, int N) {
    __shared__ int sh[256];
    int base = threadIdx.x * 4;
    int v[4]; int tsum = 0;
#pragma unroll
    for (int i = 0; i < 4; ++i) { int idx = base + i; v[i] = (idx < nbuk) ? bcount[idx] : 0; tsum += v[i]; }
    sh[threadIdx.x] = tsum;
    __syncthreads();
#pragma unroll
    for (int off = 1; off < 256; off <<= 1) {
        int y = (threadIdx.x >= (unsigned)off) ? sh[threadIdx.x - off] : 0;
        __syncthreads();
        sh[threadIdx.x] += y;
        __syncthreads();
    }
    int ex = sh[threadIdx.x] - tsum;
#pragma unroll
    for (int i = 0; i < 4; ++i) {
        int idx = base + i;
        if (idx < nbuk) { bbase[idx] = ex; ex += v[i]; }
        else if (idx == nbuk) { bbase[idx] = ex; offsets[N] = ex; }  // = E
    }
}

// ---------------- Phase A: scatter into buckets (deterministic chunk bases) ----------------

__global__ __launch_bounds__(512) void binA_kernel(const int* __restrict__ rowv,
                                                   const int* __restrict__ colv,
                                                   const int* __restrict__ chist,
                                                   const int* __restrict__ bbase,
                                                   int* __restrict__ pairs,
                                                   int E, int nbuk) {
    __shared__ int pos[400];
    int base = blockIdx.x * BINA_CHUNK;
    int end = min(base + BINA_CHUNK, E);
    for (int b = threadIdx.x; b < nbuk; b += 512)
        pos[b] = bbase[b] + chist[(size_t)blockIdx.x * nbuk + b];
    __syncthreads();
    int e = base + threadIdx.x * 4;
    for (; e + 4 <= end; e += 2048) {
        int4 c4 = *(const int4*)&colv[e];
        int4 r4 = *(const int4*)&rowv[e];
        int g0 = atomicAdd(&pos[c4.x >> BSHIFT], 1); pairs[g0] = (r4.x << BSHIFT) | (c4.x & BMASK);
        int g1 = atomicAdd(&pos[c4.y >> BSHIFT], 1); pairs[g1] = (r4.y << BSHIFT) | (c4.y & BMASK);
        int g2 = atomicAdd(&pos[c4.z >> BSHIFT], 1); pairs[g2] = (r4.z << BSHIFT) | (c4.z & BMASK);
        int g3 = atomicAdd(&pos[c4.w >> BSHIFT], 1); pairs[g3] = (r4.w << BSHIFT) | (c4.w & BMASK);
    }
    for (; e < end; ++e) {
        int c = colv[e];
        int g = atomicAdd(&pos[c >> BSHIFT], 1);
        pairs[g] = (rowv[e] << BSHIFT) | (c & BMASK);
    }
}

// ---------------- Phase B: per bucket — node hist, scan, offsets+dinv, scatter ----------------

__global__ __launch_bounds__(512) void binB_kernel(const int* __restrict__ pairs,
                                                   const int* __restrict__ bbase,
                                                   int* __restrict__ offsets,
                                                   float* __restrict__ dinv,
                                                   int* __restrict__ edge_src, int N) {
    __shared__ int lcnt[256];
    __shared__ int sc[256];
    __shared__ int lcur[256];
    int nodeBeg = blockIdx.x << BSHIFT;
    int segBeg = bbase[blockIdx.x];
    int segEnd = bbase[blockIdx.x + 1];
    if (threadIdx.x < 256) lcnt[threadIdx.x] = 0;
    __syncthreads();
    for (int e = segBeg + threadIdx.x; e < segEnd; e += 512)
        atomicAdd(&lcnt[pairs[e] & BMASK], 1);
    __syncthreads();
    int v = (threadIdx.x < 256) ? lcnt[threadIdx.x] : 0;
    if (threadIdx.x < 256) sc[threadIdx.x] = v;
    __syncthreads();
    for (int off = 1; off < 256; off <<= 1) {
        int y = 0;
        if (threadIdx.x < 256 && threadIdx.x >= (unsigned)off) y = sc[threadIdx.x - off];
        __syncthreads();
        if (threadIdx.x < 256) sc[threadIdx.x] += y;
        __syncthreads();
    }
    if (threadIdx.x < 256) {
        int ex = sc[threadIdx.x] - v;
        lcur[threadIdx.x] = ex;
        int node = nodeBeg + threadIdx.x;
        if (node < N) {
            offsets[node] = segBeg + ex;
            dinv[node] = rsqrtf((float)(v + 1));
        }
    }
    __syncthreads();
    for (int e = segBeg + threadIdx.x; e < segEnd; e += 512) {
        int p = pairs[e];
        int rel = atomicAdd(&lcur[p & BMASK], 1);
        edge_src[segBeg + rel] = p >> BSHIFT;
    }
}

// ---------------- GEMM + dinv scale, fp16 out ----------------
// 2 nodes x 4 outs per thread; packed-fp32 (v2f) accumulators.

template <int K, int NOUT>
__global__ __launch_bounds__(32 * (NOUT / 4)) void gemm_scale(const float* __restrict__ in_,
                                                              const float* __restrict__ W,
                                                              const float* __restrict__ dinv,
                                                              __half* __restrict__ out, int N) {
    constexpr int TPB = 32 * (NOUT / 4);      // 512 (NOUT=64) / 256 (NOUT=32)
    constexpr int KS = (K > 64) ? 64 : K;     // stage depth
    constexpr int XPITCH = KS + 4;
    __shared__ float xs[64 * XPITCH];
    __shared__ float ws[KS * NOUT];

    const int tid = threadIdx.x;
    const int nodeBase = blockIdx.x * 64;

    const int jg = tid % (NOUT / 4);
    const int ng = tid / (NOUT / 4);          // 0..31, 2 nodes each

    v2f acc[2][2];
#pragma unroll
    for (int i = 0; i < 2; ++i)
#pragma unroll
        for (int j = 0; j < 2; ++j) acc[i][j] = (v2f){0.f, 0.f};

    for (int kh = 0; kh < K / KS; ++kh) {
        if (kh) __syncthreads();   // previous compute done before overwrite
        for (int i = tid; i < KS * NOUT / 4; i += TPB)
            *(float4*)&ws[i * 4] = *(const float4*)&W[(size_t)kh * KS * NOUT + i * 4];
        for (int i = tid; i < 64 * KS / 4; i += TPB) {
            int row = i / (KS / 4), c = i % (KS / 4);
            int src = nodeBase + row; if (src >= N) src = N - 1;
            *(float4*)&xs[row * XPITCH + c * 4] =
                *(const float4*)&in_[(size_t)src * K + kh * KS + c * 4];
        }
        __syncthreads();

#pragma unroll 4
        for (int kc = 0; kc < KS / 4; ++kc) {
            float4 xv[2], wv[4];
#pragma unroll
            for (int ni = 0; ni < 2; ++ni)
                xv[ni] = *(const float4*)&xs[(ng * 2 + ni) * XPITCH + kc * 4];
#pragma unroll
            for (int t = 0; t < 4; ++t)
                wv[t] = *(const float4*)&ws[(kc * 4 + t) * NOUT + jg * 4];
#pragma unroll
            for (int ni = 0; ni < 2; ++ni) {
                float xk[4] = {xv[ni].x, xv[ni].y, xv[ni].z, xv[ni].w};
#pragma unroll
                for (int t = 0; t < 4; ++t) {
                    v2f xb = {xk[t], xk[t]};
                    v2f wlo = {wv[t].x, wv[t].y};
                    v2f whi = {wv[t].z, wv[t].w};
                    acc[ni][0] += xb * wlo;     // v_pk_fma_f32
                    acc[ni][1] += xb * whi;
                }
            }
        }
    }

#pragma unroll
    for (int ni = 0; ni < 2; ++ni) {
        int node = nodeBase + ng * 2 + ni;
        if (node < N) {
            float dn = dinv[node];
            __half2* op = (__half2*)(out + (size_t)node * NOUT + jg * 4);
            op[0] = __floats2half2_rn(acc[ni][0].x * dn, acc[ni][0].y * dn);
            op[1] = __floats2half2_rn(acc[ni][1].x * dn, acc[ni][1].y * dn);
        }
    }
}

// ---------------- Pull aggregation: float4 (16B) gathers, shfl-broadcast indices ----------------
// v2f accumulators (v_pk_add_f32).

template <int F, bool RELU>
__global__ __launch_bounds__(256) void agg_pull(const __half* __restrict__ h,
                                                const float* __restrict__ dinv,
                                                const float* __restrict__ bias,
                                                const int* __restrict__ edge_src,
                                                const int* __restrict__ offsets,
                                                float* __restrict__ out, int N) {
    constexpr int LPN = F / 8;        // lanes per node: F=64 -> 8, F=32 -> 4
    constexpr int GPW = 64 / LPN;     // nodes per wave: 8 / 16
    constexpr int UNR = LPN;          // edges per iteration per node
    int lane = threadIdx.x & 63;
    int wave = (blockIdx.x * 256 + (int)threadIdx.x) >> 6;
    int g = lane / LPN;
    int fl = lane % LPN;              // 16B slice index within row
    int gbase = lane & ~(LPN - 1);    // first lane of my group
    int node = wave * GPW + g;
    if (node >= N) return;
    float dn = dinv[node];
    int beg = offsets[node], end = offsets[node + 1];
    const float4* __restrict__ hp4 = (const float4*)h;   // row stride = LPN float4s

    // self-loop
    float4 sv = hp4[(size_t)node * LPN + fl];
    float2 s0 = __half22float2(*(const __half2*)&sv.x);
    float2 s1 = __half22float2(*(const __half2*)&sv.y);
    float2 s2 = __half22float2(*(const __half2*)&sv.z);
    float2 s3 = __half22float2(*(const __half2*)&sv.w);
    v2f aA[4] = {{s0.x, s0.y}, {s1.x, s1.y}, {s2.x, s2.y}, {s3.x, s3.y}};
    v2f aB[4] = {{0.f, 0.f}, {0.f, 0.f}, {0.f, 0.f}, {0.f, 0.f}};

    int j = beg;
    for (; j + UNR <= end; j += UNR) {
        int smy = edge_src[j + fl];            // one index per lane
        int sk[UNR];
#pragma unroll
        for (int k = 0; k < UNR; ++k)
            sk[k] = __shfl(smy, gbase + k, 64);
        float4 v[UNR];
#pragma unroll
        for (int k = 0; k < UNR; ++k)
            v[k] = hp4[(size_t)sk[k] * LPN + fl];
#pragma unroll
        for (int k = 0; k < UNR; ++k) {
            float2 p0 = __half22float2(*(const __half2*)&v[k].x);
            float2 p1 = __half22float2(*(const __half2*)&v[k].y);
            float2 p2 = __half22float2(*(const __half2*)&v[k].z);
            float2 p3 = __half22float2(*(const __half2*)&v[k].w);
            v2f* a = (k & 1) ? aB : aA;
            a[0] += (v2f){p0.x, p0.y};
            a[1] += (v2f){p1.x, p1.y};
            a[2] += (v2f){p2.x, p2.y};
            a[3] += (v2f){p3.x, p3.y};
        }
    }
    // tail: r = end - j < UNR
    if (j < end) {
        int r = end - j;
        int smy = (fl < r) ? edge_src[j + fl] : 0;
        for (int k = 0; k < r; ++k) {
            int sk = __shfl(smy, gbase + k, 64);
            float4 v = hp4[(size_t)sk * LPN + fl];
            float2 p0 = __half22float2(*(const __half2*)&v.x);
            float2 p1 = __half22float2(*(const __half2*)&v.y);
            float2 p2 = __half22float2(*(const __half2*)&v.z);
            float2 p3 = __half22float2(*(const __half2*)&v.w);
            v2f* a = (k & 1) ? aB : aA;
            a[0] += (v2f){p0.x, p0.y};
            a[1] += (v2f){p1.x, p1.y};
            a[2] += (v2f){p2.x, p2.y};
            a[3] += (v2f){p3.x, p3.y};
        }
    }

    float4 bva = *(const float4*)&bias[fl * 8];
    float4 bvb = *(const float4*)&bias[fl * 8 + 4];
    v2f t0 = aA[0] + aB[0];
    v2f t1 = aA[1] + aB[1];
    v2f t2 = aA[2] + aB[2];
    v2f t3 = aA[3] + aB[3];
    float r0 = t0.x * dn + bva.x;
    float r1 = t0.y * dn + bva.y;
    float r2 = t1.x * dn + bva.z;
    float r3 = t1.y * dn + bva.w;
    float r4 = t2.x * dn + bvb.x;
    float r5 = t2.y * dn + bvb.y;
    float r6 = t3.x * dn + bvb.z;
    float r7 = t3.y * dn + bvb.w;
    if (RELU) {
        r0 = fmaxf(r0, 0.f); r1 = fmaxf(r1, 0.f); r2 = fmaxf(r2, 0.f); r3 = fmaxf(r3, 0.f);
        r4 = fmaxf(r4, 0.f); r5 = fmaxf(r5, 0.f); r6 = fmaxf(r6, 0.f); r7 = fmaxf(r7, 0.f);
    }
    float* op = &out[(size_t)node * F + fl * 8];
    *(float4*)op = make_float4(r0, r1, r2, r3);
    *(float4*)(op + 4) = make_float4(r4, r5, r6, r7);
}

// ---------------- Decode stage 1: uv[n] = [z@W1_top | z@W1_bot] (fp16 out) ----------------
// 2 nodes per thread, 512 threads; packed-fp32 accumulators.

__global__ __launch_bounds__(512) void gemm_uv(const float* __restrict__ z,   // [N,32]
                                               const float* __restrict__ W1,  // [64,64]
                                               __half* __restrict__ uv, int N) {
    constexpr int ZPITCH = 36;
    __shared__ float zs[64 * ZPITCH];
    __shared__ float ws[64 * 64];
    const int tid = threadIdx.x;
    const int nodeBase = blockIdx.x * 64;

    for (int i = tid; i < 64 * 64 / 4; i += 512)
        *(float4*)&ws[i * 4] = *(const float4*)&W1[i * 4];
    for (int i = tid; i < 64 * 8; i += 512) {
        int row = i / 8, c = i % 8;
        int src = nodeBase + row; if (src >= N) src = N - 1;
        *(float4*)&zs[row * ZPITCH + c * 4] = *(const float4*)&z[(size_t)src * 32 + c * 4];
    }
    __syncthreads();

    const int jg = tid % 16;
    const int ng = tid / 16;     // 0..31, 2 nodes each

    v2f au[2][2], av[2][2];
#pragma unroll
    for (int i = 0; i < 2; ++i)
#pragma unroll
        for (int j = 0; j < 2; ++j) { au[i][j] = (v2f){0.f, 0.f}; av[i][j] = (v2f){0.f, 0.f}; }

#pragma unroll 4
    for (int kc = 0; kc < 8; ++kc) {            // K = 32
        float4 xv[2], wu[4], wv2[4];
#pragma unroll
        for (int ni = 0; ni < 2; ++ni)
            xv[ni] = *(const float4*)&zs[(ng * 2 + ni) * ZPITCH + kc * 4];
#pragma unroll
        for (int t = 0; t < 4; ++t) {
            wu[t]  = *(const float4*)&ws[(kc * 4 + t) * 64 + jg * 4];
            wv2[t] = *(const float4*)&ws[(32 + kc * 4 + t) * 64 + jg * 4];
        }
#pragma unroll
        for (int ni = 0; ni < 2; ++ni) {
            float xk[4] = {xv[ni].x, xv[ni].y, xv[ni].z, xv[ni].w};
#pragma unroll
            for (int t = 0; t < 4; ++t) {
                v2f xb = {xk[t], xk[t]};
                au[ni][0] += xb * (v2f){wu[t].x, wu[t].y};
                au[ni][1] += xb * (v2f){wu[t].z, wu[t].w};
                av[ni][0] += xb * (v2f){wv2[t].x, wv2[t].y};
                av[ni][1] += xb * (v2f){wv2[t].z, wv2[t].w};
            }
        }
    }

#pragma unroll
    for (int ni = 0; ni < 2; ++ni) {
        int node = nodeBase + ng * 2 + ni;
        if (node < N) {
            __half2* pu = (__half2*)(uv + (size_t)node * 128 + jg * 4);
            pu[0] = __floats2half2_rn(au[ni][0].x, au[ni][0].y);
            pu[1] = __floats2half2_rn(au[ni][1].x, au[ni][1].y);
            __half2* pv = (__half2*)(uv + (size_t)node * 128 + 64 + jg * 4);
            pv[0] = __floats2half2_rn(av[ni][0].x, av[ni][0].y);
            pv[1] = __floats2half2_rn(av[ni][1].x, av[ni][1].y);
        }
    }
}

// ---------------- Decode stage 2: link_pred[e] = relu(u[a]+v[b]+b1)·w2 + b2 ----------------
// 8 lanes/edge, float4 (16B) uv loads, 3-deep shuffle reduce.

__global__ __launch_bounds__(256) void decode_edge(const __half* __restrict__ uv,
                                                   const int* __restrict__ eli, int EL,
                                                   const float* __restrict__ lpb1,
                                                   const float* __restrict__ lpW2,
                                                   const float* __restrict__ lpb2,
                                                   float* __restrict__ out) {
    const int sub = threadIdx.x & 7;
    float4 b1a = *(const float4*)&lpb1[sub * 8];
    float4 b1b = *(const float4*)&lpb1[sub * 8 + 4];
    float4 w2a = *(const float4*)&lpW2[sub * 8];
    float4 w2b = *(const float4*)&lpW2[sub * 8 + 4];
    const float b2v = lpb2[0];
    int e = blockIdx.x * 32 + (threadIdx.x >> 3);
    if (e >= EL) return;
    int a = eli[e], b = eli[EL + e];
    float4 ra = *(const float4*)(uv + (size_t)a * 128 + sub * 8);        // 16B: 8 halfs of u[a]
    float4 rb = *(const float4*)(uv + (size_t)b * 128 + 64 + sub * 8);   // 16B: 8 halfs of v[b]
    float2 a01 = __half22float2(*(const __half2*)&ra.x);
    float2 a23 = __half22float2(*(const __half2*)&ra.y);
    float2 a45 = __half22float2(*(const __half2*)&ra.z);
    float2 a67 = __half22float2(*(const __half2*)&ra.w);
    float2 b01 = __half22float2(*(const __half2*)&rb.x);
    float2 b23 = __half22float2(*(const __half2*)&rb.y);
    float2 b45 = __half22float2(*(const __half2*)&rb.z);
    float2 b67 = __half22float2(*(const __half2*)&rb.w);
    float p = fmaxf(a01.x + b01.x + b1a.x, 0.f) * w2a.x;
    p = fmaf(fmaxf(a01.y + b01.y + b1a.y, 0.f), w2a.y, p);
    p = fmaf(fmaxf(a23.x + b23.x + b1a.z, 0.f), w2a.z, p);
    p = fmaf(fmaxf(a23.y + b23.y + b1a.w, 0.f), w2a.w, p);
    p = fmaf(fmaxf(a45.x + b45.x + b1b.x, 0.f), w2b.x, p);
    p = fmaf(fmaxf(a45.y + b45.y + b1b.y, 0.f), w2b.y, p);
    p = fmaf(fmaxf(a67.x + b67.x + b1b.z, 0.f), w2b.z, p);
    p = fmaf(fmaxf(a67.y + b67.y + b1b.w, 0.f), w2b.w, p);
    p += __shfl_down(p, 4, 8);
    p += __shfl_down(p, 2, 8);
    p += __shfl_down(p, 1, 8);
    if (sub == 0) out[e] = p + b2v;
}

// ---------------- launch ----------------

extern "C" void kernel_launch(void* const* d_in, const int* in_sizes, int n_in,
                              void* d_out, int out_size, void* d_ws, size_t ws_size,
                              hipStream_t stream) {
    const float* x    = (const float*)d_in[0];
    const int* ei     = (const int*)d_in[1];
    const int* eli    = (const int*)d_in[2];
    const float* W1   = (const float*)d_in[3];
    const float* b1   = (const float*)d_in[4];
    const float* W2   = (const float*)d_in[5];
    const float* b2   = (const float*)d_in[6];
    const float* W3   = (const float*)d_in[7];
    const float* b3   = (const float*)d_in[8];
    const float* lpW1 = (const float*)d_in[9];
    const float* lpb1 = (const float*)d_in[10];
    const float* lpW2 = (const float*)d_in[11];
    const float* lpb2 = (const float*)d_in[12];

    const int N  = in_sizes[0] / 128;   // 100000
    const int E  = in_sizes[1] / 2;     // 3200000
    const int EL = in_sizes[2] / 2;     // 1000000

    char* p = (char*)d_ws;
    auto alloc = [&](size_t bytes) { void* r = (void*)p; p += (bytes + 255) & ~(size_t)255; return r; };
    float* dinv     = (float*)alloc((size_t)N * 4);
    int*   offsets  = (int*)alloc((size_t)(N + 1) * 4);
    int*   bcount   = (int*)alloc(1024 * 4);
    int*   bbase    = (int*)alloc(1024 * 4);
    int*   edge_src = (int*)alloc((size_t)E * 4);
    __half* bufG    = (__half*)alloc((size_t)N * 64 * 2);   // fp16 messages h'
    float* bufZ     = (float*)alloc((size_t)N * 64 * 4);    // fp32 z1/z2
    __half* uvbuf   = (__half*)alloc((size_t)N * 128 * 2);  // fp16 uv
    int*   pairs    = (int*)uvbuf;  // alias: pairs (12.8MB) dead before gemm_uv writes uv
    int*   chist    = (int*)bufZ;   // alias: chist (612KB) dead before agg_pull writes bufZ

    const int* rowv = ei;        // edge_index[0] = source
    const int* colv = ei + E;    // edge_index[1] = target

    int nbuk = (N + BMASK) >> BSHIFT;                // 391
    int nchunk = (E + BINA_CHUNK - 1) / BINA_CHUNK;  // 391 (<=1024 required by colscan)

    bhist_kernel<<<nchunk, 512, 0, stream>>>(colv, chist, E, nbuk);
    colscan_kernel<<<nbuk, 256, 0, stream>>>(chist, bcount, nchunk, nbuk);
    bscan_kernel<<<1, 256, 0, stream>>>(bcount, bbase, nbuk, offsets, N);
    binA_kernel<<<nchunk, 512, 0, stream>>>(rowv, colv, chist, bbase, pairs, E, nbuk);
    binB_kernel<<<nbuk, 512, 0, stream>>>(pairs, bbase, offsets, dinv, edge_src, N);

    float* zout = (float*)d_out + EL;   // z lives in the output tail (float32)

    int gblocks = (N + 63) / 64;  // 1563

    // agg_pull: F=64 -> 8 nodes/wave * 4 waves = 32 nodes/block;
    //           F=32 -> 16 nodes/wave * 4 waves = 64 nodes/block.
    int aggblocks64 = (N + 31) / 32;   // 3125
    int aggblocks32 = (N + 63) / 64;   // 1563

    // layer 1: x[N,128] -> bufG h' (fp16) -> bufZ (fp32, relu)
    gemm_scale<128, 64><<<gblocks, 512, 0, stream>>>(x, W1, dinv, bufG, N);
    agg_pull<64, true><<<aggblocks64, 256, 0, stream>>>(bufG, dinv, b1, edge_src, offsets, bufZ, N);
    // layer 2
    gemm_scale<64, 64><<<gblocks, 512, 0, stream>>>(bufZ, W2, dinv, bufG, N);
    agg_pull<64, true><<<aggblocks64, 256, 0, stream>>>(bufG, dinv, b2, edge_src, offsets, bufZ, N);
    // layer 3: 32-wide, write z directly into d_out tail
    gemm_scale<64, 32><<<gblocks, 256, 0, stream>>>(bufZ, W3, dinv, bufG, N);
    agg_pull<32, false><<<aggblocks32, 256, 0, stream>>>(bufG, dinv, b3, edge_src, offsets, zout, N);
    // decode: per-node uv precompute (fp16), then per-edge gather+epilogue
    gemm_uv<<<gblocks, 512, 0, stream>>>(zout, lpW1, uvbuf, N);
    decode_edge<<<(EL + 31) / 32, 256, 0, stream>>>(uvbuf, eli, EL, lpb1, lpW2, lpb2, (float*)d_out);
}